// Round 1
// baseline (545.778 us; speedup 1.0000x reference)
//
#include <hip/hip_runtime.h>
#include <math.h>

#define CD 512
#define NNODE 64
#define TPAD 520   // bf16 tile row stride: 1040 B, measured 0 bank conflicts

typedef __attribute__((ext_vector_type(8)))  short bfrag8;   // 8 bf16 (4 VGPRs)
typedef __attribute__((ext_vector_type(8)))  short sv8;
typedef __attribute__((ext_vector_type(4)))  short sv4;
typedef __attribute__((ext_vector_type(16))) float f32x16;

__device__ __forceinline__ unsigned short f2bf(float f) {
    union { float f; unsigned u; } v; v.f = f;
    unsigned r = (v.u + 0x7fffu + ((v.u >> 16) & 1u)) >> 16;
    return (unsigned short)r;
}
__device__ __forceinline__ float bf2f(unsigned short u) {
    union { unsigned u; float f; } v; v.u = ((unsigned)u) << 16;
    return v.f;
}

// async global->LDS, 16B per lane, dest = wave-uniform base + lane*16
__device__ __forceinline__ void gload_lds16(const void* g, void* s) {
    __builtin_amdgcn_global_load_lds(
        (const __attribute__((address_space(1))) unsigned int*)g,
        (__attribute__((address_space(3))) unsigned int*)s, 16, 0, 0);
}

// ---- pack 10 weights into 32x32x16 MFMA-B fragment order ----
// Bp[kt(32)][g(16)][lane][i(8)] = W[c=g*32+(l&31)][k=kt*16+(l>>5)*8+i]
__global__ void pack32_k(const float* __restrict__ W0, const float* __restrict__ W1,
                         const float* __restrict__ W2, const float* __restrict__ W3,
                         const float* __restrict__ W4, const float* __restrict__ W5,
                         const float* __restrict__ W6, const float* __restrict__ W7,
                         const float* __restrict__ W8, const float* __restrict__ W9,
                         unsigned short* __restrict__ out)
{
    const float* Ws[10] = {W0,W1,W2,W3,W4,W5,W6,W7,W8,W9};
    int kt = blockIdx.x, ct = blockIdx.y, wi = blockIdx.z, l = threadIdx.x;
    const float* W = Ws[wi];
    int c  = ct * 32 + (l & 31);
    int k0 = kt * 16 + (l >> 5) * 8;
    const float* src = W + (size_t)c * CD + k0;
    unsigned short o[8];
    #pragma unroll
    for (int i = 0; i < 8; ++i) o[i] = f2bf(src[i]);
    unsigned short* dst = out + (size_t)wi * 262144 + ((size_t)(kt * 16 + ct) * 64 + l) * 8;
    *(bfrag8*)dst = *(bfrag8*)o;
}

// ---- projection: O = A(1024x512) @ W.T, M=64 tile per block ----
__global__ __launch_bounds__(512, 4) void proj_mfma(
    const float* __restrict__ A, const unsigned short* __restrict__ Bp4,
    float* __restrict__ O0, float* __restrict__ O1,
    float* __restrict__ O2, float* __restrict__ O3)
{
    __shared__ unsigned short tile[64 * TPAD];
    const int rb = blockIdx.x * 64, widx = blockIdx.y;
    float* outs[4] = {O0,O1,O2,O3};
    float* out = outs[widx];
    const unsigned short* Bp = Bp4 + (size_t)widx * 262144;
    const int t = threadIdx.x, l = t & 63, w = t >> 6;
    const int stripe = w & 1, H = w >> 1;

    const float* src = A + (size_t)rb * CD;
    #pragma unroll 4
    for (int it = 0; it < 16; ++it) {
        int flat = it * 2048 + t * 4;
        float4 v4 = *(const float4*)(src + flat);
        int r = flat >> 9, c = flat & 511;
        sv4 pk; pk.x = (short)f2bf(v4.x); pk.y = (short)f2bf(v4.y);
        pk.z = (short)f2bf(v4.z); pk.w = (short)f2bf(v4.w);
        *(sv4*)(tile + r * TPAD + c) = pk;
    }
    __syncthreads();

    f32x16 acc[4] = {};
    const unsigned short* aptr = tile + (size_t)(stripe * 32 + (l & 31)) * TPAD + (l >> 5) * 8;
    const unsigned short* bptr = Bp + ((size_t)(H * 4) * 64 + l) * 8;

    bfrag8 a0, a1, b0[4], b1[4];
    a0 = *(const bfrag8*)aptr;
    #pragma unroll
    for (int tt = 0; tt < 4; ++tt) b0[tt] = *(const bfrag8*)(bptr + tt * 512);
    for (int k2 = 0; k2 < 16; ++k2) {
        int kt1 = 2 * k2 + 1;
        a1 = *(const bfrag8*)(aptr + kt1 * 16);
        #pragma unroll
        for (int tt = 0; tt < 4; ++tt) b1[tt] = *(const bfrag8*)(bptr + (size_t)kt1 * 8192 + tt * 512);
        #pragma unroll
        for (int tt = 0; tt < 4; ++tt)
            acc[tt] = __builtin_amdgcn_mfma_f32_32x32x16_bf16(a0, b0[tt], acc[tt], 0, 0, 0);
        int kt2 = (k2 == 15) ? 31 : (2 * k2 + 2);
        a0 = *(const bfrag8*)(aptr + kt2 * 16);
        #pragma unroll
        for (int tt = 0; tt < 4; ++tt) b0[tt] = *(const bfrag8*)(bptr + (size_t)kt2 * 8192 + tt * 512);
        #pragma unroll
        for (int tt = 0; tt < 4; ++tt)
            acc[tt] = __builtin_amdgcn_mfma_f32_32x32x16_bf16(a1, b1[tt], acc[tt], 0, 0, 0);
    }
    const int cbase = H * 128 + (l & 31);
    #pragma unroll
    for (int r = 0; r < 16; ++r) {
        int rl = (r & 3) + 8 * (r >> 2) + 4 * (l >> 5);
        int row = rb + stripe * 32 + rl;
        #pragma unroll
        for (int tt = 0; tt < 4; ++tt)
            out[(size_t)row * CD + cbase + tt * 32] = acc[tt][r];
    }
}

// ---- fused edge kernel: one (b,i) pair per block, M=64 ----
// Wave tile 64 rows x 64 cols: 2 A-frags x 2 B-frags per k-step -> B read once
// per block (512 KB from L2, halved). Softmax-over-j is register-resident:
// channel c lives in lanes (l, l^32) of wave c>>6 only.
template<bool INBF, bool OUTBF>
__global__ __launch_bounds__(512, 4) void edge_mfma(
    const void* __restrict__ einv, void* __restrict__ eoutv,
    const float* __restrict__ Vix, const float* __restrict__ Vjx,
    const float* __restrict__ Ujx, const unsigned short* __restrict__ Bp,
    const float* __restrict__ ge, const float* __restrict__ be,
    float* __restrict__ agg)
{
    __shared__ unsigned short tile[64 * TPAD];   // 66.6 KB (A staging, read-only after barrier)
    __shared__ float sums[64][8][2];             // per-row LN partials per wave (4 KB)
    __shared__ float rowstat[64][2];             // mean, rsqrt (0.5 KB)

    const int bi = blockIdx.x;                   // b*64 + i
    const int brow = bi & ~63;                   // b*64
    const int t = threadIdx.x, l = t & 63, w = t >> 6;   // w in [0,8): 64-col slice
    const int hi = l >> 5;

    // ---- B prefetch for k-step 0 (independent of staging) ----
    const unsigned short* bptr = Bp + ((size_t)(2 * w) * 64 + l) * 8;
    bfrag8 b0[2], b1[2];
    #pragma unroll
    for (int ct = 0; ct < 2; ++ct) b0[ct] = *(const bfrag8*)(bptr + ct * 512);

    // ---- stage edge tile -> bf16 LDS ----
    if (INBF) {
        const unsigned short* src = (const unsigned short*)einv + (size_t)bi * 65536;
        #pragma unroll
        for (int it = 0; it < 8; ++it) {
            int row = it * 8 + w;
            gload_lds16(src + (size_t)row * 512 + l * 8, tile + (size_t)row * TPAD);
        }
    } else {
        const float* src = (const float*)einv + (size_t)bi * 32768;
        #pragma unroll 4
        for (int it = 0; it < 16; ++it) {
            int flat = it * 2048 + t * 4;
            float4 v4 = *(const float4*)(src + flat);
            int r = flat >> 9, c = flat & 511;
            sv4 pk; pk.x = (short)f2bf(v4.x); pk.y = (short)f2bf(v4.y);
            pk.z = (short)f2bf(v4.z); pk.w = (short)f2bf(v4.w);
            *(sv4*)(tile + r * TPAD + c) = pk;
        }
    }
    __syncthreads();

    // ---- K-loop: 32 steps of K=16; 2 A-frags (rows) x 2 B-frags (cols) ----
    f32x16 acc[2][2] = {};
    const unsigned short* aptr = tile + (size_t)(l & 31) * TPAD + hi * 8;

    bfrag8 a0[2], a1[2];
    #pragma unroll
    for (int rt = 0; rt < 2; ++rt) a0[rt] = *(const bfrag8*)(aptr + rt * 32 * TPAD);
    for (int k2 = 0; k2 < 16; ++k2) {
        int kt1 = 2 * k2 + 1;
        #pragma unroll
        for (int rt = 0; rt < 2; ++rt) a1[rt] = *(const bfrag8*)(aptr + rt * 32 * TPAD + kt1 * 16);
        #pragma unroll
        for (int ct = 0; ct < 2; ++ct) b1[ct] = *(const bfrag8*)(bptr + (size_t)kt1 * 8192 + ct * 512);
        #pragma unroll
        for (int rt = 0; rt < 2; ++rt)
            #pragma unroll
            for (int ct = 0; ct < 2; ++ct)
                acc[rt][ct] = __builtin_amdgcn_mfma_f32_32x32x16_bf16(a0[rt], b0[ct], acc[rt][ct], 0, 0, 0);
        int kt2 = (k2 == 15) ? 31 : (2 * k2 + 2);
        #pragma unroll
        for (int rt = 0; rt < 2; ++rt) a0[rt] = *(const bfrag8*)(aptr + rt * 32 * TPAD + kt2 * 16);
        #pragma unroll
        for (int ct = 0; ct < 2; ++ct) b0[ct] = *(const bfrag8*)(bptr + (size_t)kt2 * 8192 + ct * 512);
        #pragma unroll
        for (int rt = 0; rt < 2; ++rt)
            #pragma unroll
            for (int ct = 0; ct < 2; ++ct)
                acc[rt][ct] = __builtin_amdgcn_mfma_f32_32x32x16_bf16(a1[rt], b1[ct], acc[rt][ct], 0, 0, 0);
    }

    // ---- epilogue: m = acc + vix + vjx; per-row LN partial stats ----
    const int c0 = w * 64 + (l & 31);
    const float* VixB = Vix + (size_t)bi * CD;
    const float vix0 = VixB[c0], vix1 = VixB[c0 + 32];
    const float gev[2] = {ge[c0], ge[c0 + 32]};
    const float bev[2] = {be[c0], be[c0 + 32]};
    const float* VjxB = Vjx + (size_t)brow * CD;

    #pragma unroll
    for (int rt = 0; rt < 2; ++rt) {
        float s1[16], s2[16];
        #pragma unroll
        for (int r = 0; r < 16; ++r) {
            int rl = (r & 3) + 8 * (r >> 2) + 4 * hi;
            int row = rt * 32 + rl;
            const float* vjr = VjxB + (size_t)row * CD;
            float m0 = acc[rt][0][r] + vix0 + vjr[c0];
            float m1 = acc[rt][1][r] + vix1 + vjr[c0 + 32];
            acc[rt][0][r] = m0; acc[rt][1][r] = m1;
            s1[r] = m0 + m1; s2[r] = m0 * m0 + m1 * m1;
        }
        #pragma unroll
        for (int off = 1; off < 32; off <<= 1) {
            #pragma unroll
            for (int r = 0; r < 16; ++r) {
                s1[r] += __shfl_xor(s1[r], off, 64);
                s2[r] += __shfl_xor(s2[r], off, 64);
            }
        }
        if ((l & 31) == 0) {
            #pragma unroll
            for (int r = 0; r < 16; ++r) {
                int rl = (r & 3) + 8 * (r >> 2) + 4 * hi;
                float2 p; p.x = s1[r]; p.y = s2[r];
                *(float2*)&sums[rt * 32 + rl][w][0] = p;
            }
        }
    }
    __syncthreads();

    // ---- finalize per-row mean / rsqrt ----
    if (t < 64) {
        float t1 = 0.f, t2 = 0.f;
        #pragma unroll
        for (int ww = 0; ww < 8; ++ww) { t1 += sums[t][ww][0]; t2 += sums[t][ww][1]; }
        float mean = t1 * (1.f / 512.f);
        float var  = t2 * (1.f / 512.f) - mean * mean;
        float2 mr; mr.x = mean; mr.y = rsqrtf(var + 1e-5f);
        *(float2*)&rowstat[t][0] = mr;
    }
    __syncthreads();

    // ---- env = edge + relu(LN(m)); write; wv = exp(sigmoid(env)) in regs ----
    #pragma unroll
    for (int rt = 0; rt < 2; ++rt) {
        #pragma unroll
        for (int r = 0; r < 16; ++r) {
            int rl = (r & 3) + 8 * (r >> 2) + 4 * hi;
            int row = rt * 32 + rl;
            float2 mr = *(const float2*)&rowstat[row][0];
            const unsigned short* trow = tile + (size_t)row * TPAD;
            #pragma unroll
            for (int ct = 0; ct < 2; ++ct) {
                int c = c0 + ct * 32;
                float ln  = (acc[rt][ct][r] - mr.x) * mr.y * gev[ct] + bev[ct];
                float env = bf2f(trow[c]) + fmaxf(ln, 0.f);
                if (OUTBF) ((unsigned short*)eoutv)[(size_t)bi * 65536 + row * 512 + c] = f2bf(env);
                else       ((float*)eoutv)[(size_t)bi * 32768 + row * 512 + c] = env;
                float sg = 1.f / (1.f + __expf(-env));
                acc[rt][ct][r] = __expf(sg);
            }
        }
    }

    // ---- register-resident softmax-over-j + aggregate (no LDS, no barrier) ----
    const float* UjxB = Ujx + (size_t)brow * CD;
    #pragma unroll
    for (int ct = 0; ct < 2; ++ct) {
        int c = c0 + ct * 32;
        float den = 0.f, num = 0.f;
        #pragma unroll
        for (int rt = 0; rt < 2; ++rt) {
            #pragma unroll
            for (int r = 0; r < 16; ++r) {
                int rl = (r & 3) + 8 * (r >> 2) + 4 * hi;
                int row = rt * 32 + rl;
                float wv = acc[rt][ct][r];
                float uv = UjxB[(size_t)row * CD + c];
                den += wv; num = fmaf(wv, uv, num);
            }
        }
        den += __shfl_xor(den, 32, 64);
        num += __shfl_xor(num, 32, 64);
        if (l < 32) agg[(size_t)bi * CD + c] = num / (den * (float)NNODE);
    }
}

// ---- x update: x = relu(res + LN(XU + agg)) ----
__global__ __launch_bounds__(256) void xupd_kernel(
    const float* __restrict__ res,
    const float* __restrict__ XU,
    const float* __restrict__ aggp,
    const float* __restrict__ gv, const float* __restrict__ bv,
    float* __restrict__ xout)
{
    int r = blockIdx.x * 4 + (threadIdx.x >> 6);
    int lane = threadIdx.x & 63;
    const float* xu = XU + (size_t)r * CD;
    const float* ag = aggp + (size_t)r * CD;
    float y[8]; float s1 = 0.f, s2 = 0.f;
    #pragma unroll
    for (int u = 0; u < 8; ++u) {
        int c = lane + u * 64;
        float v = xu[c] + ag[c];
        y[u] = v; s1 += v; s2 += v * v;
    }
    #pragma unroll
    for (int off = 32; off > 0; off >>= 1) {
        s1 += __shfl_xor(s1, off, 64);
        s2 += __shfl_xor(s2, off, 64);
    }
    float mean = s1 * (1.f / 512.f);
    float var  = s2 * (1.f / 512.f) - mean * mean;
    float rs   = rsqrtf(var + 1e-5f);
    const float* rr = res + (size_t)r * CD;
    float* xo = xout + (size_t)r * CD;
    #pragma unroll
    for (int u = 0; u < 8; ++u) {
        int c = lane + u * 64;
        float ln = (y[u] - mean) * rs * gv[c] + bv[c];
        xo[c] = fmaxf(rr[c] + ln, 0.f);
    }
}

extern "C" void kernel_launch(void* const* d_in, const int* in_sizes, int n_in,
                              void* d_out, int out_size, void* d_ws, size_t ws_size,
                              hipStream_t stream)
{
    const float* x    = (const float*)d_in[0];
    const float* edge = (const float*)d_in[1];
    const float* W[10];
    for (int i = 0; i < 10; ++i) W[i] = (const float*)d_in[2 + i];
    // 0 WA1, 1 WB1, 2 WE1, 3 WU1, 4 WV1, 5 WA2, 6 WB2, 7 WE2, 8 WU2, 9 WV2
    const float* ge1 = (const float*)d_in[12];
    const float* gv1 = (const float*)d_in[13];
    const float* ge2 = (const float*)d_in[14];
    const float* gv2 = (const float*)d_in[15];
    const float* be1 = (const float*)d_in[16];
    const float* bv1 = (const float*)d_in[17];
    const float* be2 = (const float*)d_in[18];
    const float* bv2 = (const float*)d_in[19];

    char* wsb = (char*)d_ws;
    unsigned short* P32 = (unsigned short*)wsb;               // 10 x 512 KB = 5 MB
    float* Vix = (float*)(wsb + (size_t)6  * 1048576);
    float* Vjx = (float*)(wsb + (size_t)8  * 1048576);
    float* Ujx = (float*)(wsb + (size_t)10 * 1048576);
    float* XU  = (float*)(wsb + (size_t)12 * 1048576);
    float* agg = (float*)(wsb + (size_t)14 * 1048576);
    float* x1  = (float*)(wsb + (size_t)16 * 1048576);

    float* xout  = (float*)d_out;
    float* eintF = xout + (size_t)524288;     // edge region (bf16 lives in slot's first half)

    // pack order: 0 WA1, 1 WB1, 2 WV1, 3 WU1, 4 WA2, 5 WB2, 6 WV2, 7 WU2, 8 WE1, 9 WE2
    pack32_k<<<dim3(32, 16, 10), 64, 0, stream>>>(
        W[0], W[1], W[4], W[3], W[5], W[6], W[9], W[8], W[2], W[7], P32);

#define PW(i) (P32 + (size_t)(i) * 262144)
    // ---- layer 1 ----
    proj_mfma<<<dim3(16, 4), 512, 0, stream>>>(x, PW(0), Vix, Vjx, Ujx, XU);
    edge_mfma<false, true><<<1024, 512, 0, stream>>>(edge, eintF, Vix, Vjx, Ujx,
                                                     PW(8), ge1, be1, agg);
    xupd_kernel<<<256, 256, 0, stream>>>(x, XU, agg, gv1, bv1, x1);
    // ---- layer 2 ----
    proj_mfma<<<dim3(16, 4), 512, 0, stream>>>(x1, PW(4), Vix, Vjx, Ujx, XU);
    edge_mfma<true, false><<<1024, 512, 0, stream>>>(eintF, eintF, Vix, Vjx, Ujx,
                                                     PW(9), ge2, be2, agg);
    xupd_kernel<<<256, 256, 0, stream>>>(x1, XU, agg, gv2, bv2, xout);
#undef PW
}

// Round 2
// 496.529 us; speedup vs baseline: 1.0992x; 1.0992x over previous
//
#include <hip/hip_runtime.h>
#include <math.h>

#define CD 512
#define NNODE 64
#define TPAD 520   // bf16 tile row stride: 1040 B, measured 0 bank conflicts

typedef __attribute__((ext_vector_type(8)))  short bfrag8;   // 8 bf16 (4 VGPRs)
typedef __attribute__((ext_vector_type(8)))  short sv8;
typedef __attribute__((ext_vector_type(4)))  short sv4;
typedef __attribute__((ext_vector_type(16))) float f32x16;

__device__ __forceinline__ unsigned short f2bf(float f) {
    union { float f; unsigned u; } v; v.f = f;
    unsigned r = (v.u + 0x7fffu + ((v.u >> 16) & 1u)) >> 16;
    return (unsigned short)r;
}
__device__ __forceinline__ float bf2f(unsigned short u) {
    union { unsigned u; float f; } v; v.u = ((unsigned)u) << 16;
    return v.f;
}

// ---- pack 10 weights into 32x32x16 MFMA-B fragment order ----
// Bp[kt(32)][g(16)][lane][i(8)] = W[c=g*32+(l&31)][k=kt*16+(l>>5)*8+i]
__global__ void pack32_k(const float* __restrict__ W0, const float* __restrict__ W1,
                         const float* __restrict__ W2, const float* __restrict__ W3,
                         const float* __restrict__ W4, const float* __restrict__ W5,
                         const float* __restrict__ W6, const float* __restrict__ W7,
                         const float* __restrict__ W8, const float* __restrict__ W9,
                         unsigned short* __restrict__ out)
{
    const float* Ws[10] = {W0,W1,W2,W3,W4,W5,W6,W7,W8,W9};
    int kt = blockIdx.x, ct = blockIdx.y, wi = blockIdx.z, l = threadIdx.x;
    const float* W = Ws[wi];
    int c  = ct * 32 + (l & 31);
    int k0 = kt * 16 + (l >> 5) * 8;
    const float* src = W + (size_t)c * CD + k0;
    unsigned short o[8];
    #pragma unroll
    for (int i = 0; i < 8; ++i) o[i] = f2bf(src[i]);
    unsigned short* dst = out + (size_t)wi * 262144 + ((size_t)(kt * 16 + ct) * 64 + l) * 8;
    *(bfrag8*)dst = *(bfrag8*)o;
}

// ---- projection: O = A(1024x512) @ W.T, M=32 tile per block ----
// 128 blocks (vs 64): LDS 33 KB -> 4 blocks/CU, 32 waves/CU, half the
// per-block serial chain. Wave tile 32 rows x 64 cols, acc = 32 AGPR.
__global__ __launch_bounds__(512, 4) void proj_mfma(
    const float* __restrict__ A, const unsigned short* __restrict__ Bp4,
    float* __restrict__ O0, float* __restrict__ O1,
    float* __restrict__ O2, float* __restrict__ O3)
{
    __shared__ unsigned short tile[32 * TPAD];
    const int rb = blockIdx.x * 32, widx = blockIdx.y;
    float* outs[4] = {O0,O1,O2,O3};
    float* out = outs[widx];
    const unsigned short* Bp = Bp4 + (size_t)widx * 262144;
    const int t = threadIdx.x, l = t & 63, w = t >> 6;

    const float* src = A + (size_t)rb * CD;
    #pragma unroll 4
    for (int it = 0; it < 8; ++it) {
        int flat = it * 2048 + t * 4;
        float4 v4 = *(const float4*)(src + flat);
        int r = flat >> 9, c = flat & 511;
        sv4 pk; pk.x = (short)f2bf(v4.x); pk.y = (short)f2bf(v4.y);
        pk.z = (short)f2bf(v4.z); pk.w = (short)f2bf(v4.w);
        *(sv4*)(tile + r * TPAD + c) = pk;
    }
    __syncthreads();

    f32x16 acc[2] = {};
    const unsigned short* aptr = tile + (size_t)(l & 31) * TPAD + (l >> 5) * 8;
    const unsigned short* bptr = Bp + ((size_t)(2 * w) * 64 + l) * 8;

    bfrag8 a0, a1, b0[2], b1[2];
    a0 = *(const bfrag8*)aptr;
    #pragma unroll
    for (int ct = 0; ct < 2; ++ct) b0[ct] = *(const bfrag8*)(bptr + ct * 512);
    for (int k2 = 0; k2 < 16; ++k2) {
        int kt1 = 2 * k2 + 1;
        a1 = *(const bfrag8*)(aptr + kt1 * 16);
        #pragma unroll
        for (int ct = 0; ct < 2; ++ct) b1[ct] = *(const bfrag8*)(bptr + (size_t)kt1 * 8192 + ct * 512);
        #pragma unroll
        for (int ct = 0; ct < 2; ++ct)
            acc[ct] = __builtin_amdgcn_mfma_f32_32x32x16_bf16(a0, b0[ct], acc[ct], 0, 0, 0);
        int kt2 = (k2 == 15) ? 31 : (2 * k2 + 2);
        a0 = *(const bfrag8*)(aptr + kt2 * 16);
        #pragma unroll
        for (int ct = 0; ct < 2; ++ct) b0[ct] = *(const bfrag8*)(bptr + (size_t)kt2 * 8192 + ct * 512);
        #pragma unroll
        for (int ct = 0; ct < 2; ++ct)
            acc[ct] = __builtin_amdgcn_mfma_f32_32x32x16_bf16(a1, b1[ct], acc[ct], 0, 0, 0);
    }
    // C layout 32x32: col = lane&31, row = (reg&3)+8*(reg>>2)+4*(lane>>5)
    const int cbase = w * 64 + (l & 31);
    #pragma unroll
    for (int r = 0; r < 16; ++r) {
        int rl = (r & 3) + 8 * (r >> 2) + 4 * (l >> 5);
        int row = rb + rl;
        #pragma unroll
        for (int ct = 0; ct < 2; ++ct)
            out[(size_t)row * CD + cbase + ct * 32] = acc[ct][r];
    }
}

// ---- fused edge kernel: one (b,i) pair per block, M=64 ----
// R0 body (verified spill-free) + fused x-update tail: block bi owns
// agg row bi entirely, so x = relu(res + LN(XU + agg)) finishes here.
template<bool INBF, bool OUTBF>
__global__ __launch_bounds__(512, 4) void edge_mfma(
    const void* __restrict__ einv, void* __restrict__ eoutv,
    const float* __restrict__ Vix, const float* __restrict__ Vjx,
    const float* __restrict__ Ujx, const unsigned short* __restrict__ Bp,
    const float* __restrict__ ge, const float* __restrict__ be,
    const float* __restrict__ XU, const float* __restrict__ xres,
    const float* __restrict__ gv, const float* __restrict__ bv,
    float* __restrict__ xout)
{
    __shared__ unsigned short tile[64 * TPAD];   // 66.6 KB
    __shared__ float sums[64][4][2];             // [row][H-quarter][s1,s2]
    __shared__ float xs1[8], xs2[8];             // fused-xupd wave partials

    const int bi = blockIdx.x;                   // b*64 + i
    const int brow = bi & ~63;                   // b*64
    const int t = threadIdx.x, l = t & 63, w = t >> 6;
    const int stripe = w & 1, H = w >> 1;        // 2 row-stripes x 4 col-quarters

    // ---- stage edge pair -> bf16 LDS ----
    if (INBF) {
        const unsigned short* src = (const unsigned short*)einv + (size_t)bi * 65536;
        #pragma unroll 4
        for (int it = 0; it < 8; ++it) {
            int flat = it * 4096 + t * 8;
            int r = flat >> 9, c = flat & 511;
            *(sv8*)(tile + r * TPAD + c) = *(const sv8*)(src + flat);
        }
    } else {
        const float* src = (const float*)einv + (size_t)bi * 32768;
        #pragma unroll 4
        for (int it = 0; it < 16; ++it) {
            int flat = it * 2048 + t * 4;
            float4 v4 = *(const float4*)(src + flat);
            int r = flat >> 9, c = flat & 511;
            sv4 pk; pk.x = (short)f2bf(v4.x); pk.y = (short)f2bf(v4.y);
            pk.z = (short)f2bf(v4.z); pk.w = (short)f2bf(v4.w);
            *(sv4*)(tile + r * TPAD + c) = pk;
        }
    }
    __syncthreads();

    // ---- K-loop: 32 steps of K=16, zero barriers, B streamed from L2 ----
    f32x16 acc[4] = {};
    const unsigned short* aptr = tile + (size_t)(stripe * 32 + (l & 31)) * TPAD + (l >> 5) * 8;
    const unsigned short* bptr = Bp + ((size_t)(H * 4) * 64 + l) * 8;

    bfrag8 a0, a1, b0[4], b1[4];
    a0 = *(const bfrag8*)aptr;
    #pragma unroll
    for (int tt = 0; tt < 4; ++tt) b0[tt] = *(const bfrag8*)(bptr + tt * 512);
    for (int k2 = 0; k2 < 16; ++k2) {
        int kt1 = 2 * k2 + 1;
        a1 = *(const bfrag8*)(aptr + kt1 * 16);
        #pragma unroll
        for (int tt = 0; tt < 4; ++tt) b1[tt] = *(const bfrag8*)(bptr + (size_t)kt1 * 8192 + tt * 512);
        #pragma unroll
        for (int tt = 0; tt < 4; ++tt)
            acc[tt] = __builtin_amdgcn_mfma_f32_32x32x16_bf16(a0, b0[tt], acc[tt], 0, 0, 0);
        int kt2 = (k2 == 15) ? 31 : (2 * k2 + 2);
        a0 = *(const bfrag8*)(aptr + kt2 * 16);
        #pragma unroll
        for (int tt = 0; tt < 4; ++tt) b0[tt] = *(const bfrag8*)(bptr + (size_t)kt2 * 8192 + tt * 512);
        #pragma unroll
        for (int tt = 0; tt < 4; ++tt)
            acc[tt] = __builtin_amdgcn_mfma_f32_32x32x16_bf16(a1, b1[tt], acc[tt], 0, 0, 0);
    }

    // ---- epilogue: m = acc + vix + vjx; LN partial stats over 128 cols ----
    const int cbase = H * 128 + (l & 31);
    float vix[4], gev[4], bev[4];
    #pragma unroll
    for (int tt = 0; tt < 4; ++tt) {
        int c = cbase + tt * 32;
        vix[tt] = Vix[(size_t)bi * CD + c];
        gev[tt] = ge[c]; bev[tt] = be[c];
    }
    float s1[16], s2[16];
    #pragma unroll
    for (int r = 0; r < 16; ++r) {
        int rl = (r & 3) + 8 * (r >> 2) + 4 * (l >> 5);
        int rt = stripe * 32 + rl;               // row = j in [0,64)
        const float* vjr = Vjx + (size_t)(brow + rt) * CD;
        float a1_ = 0.f, a2_ = 0.f;
        #pragma unroll
        for (int tt = 0; tt < 4; ++tt) {
            float m = acc[tt][r] + vix[tt] + vjr[cbase + tt * 32];
            acc[tt][r] = m;
            a1_ += m; a2_ = fmaf(m, m, a2_);
        }
        s1[r] = a1_; s2[r] = a2_;
    }
    #pragma unroll
    for (int off = 1; off < 32; off <<= 1) {
        #pragma unroll
        for (int r = 0; r < 16; ++r) {
            s1[r] += __shfl_xor(s1[r], off, 64);
            s2[r] += __shfl_xor(s2[r], off, 64);
        }
    }
    if ((l & 31) == 0) {
        #pragma unroll
        for (int r = 0; r < 16; ++r) {
            int rl = (r & 3) + 8 * (r >> 2) + 4 * (l >> 5);
            int rt = stripe * 32 + rl;
            sums[rt][H][0] = s1[r]; sums[rt][H][1] = s2[r];
        }
    }
    __syncthreads();

    // ---- env = edge + relu(LN(m)); write; tile <- exp(sigmoid(env)) ----
    #pragma unroll
    for (int r = 0; r < 16; ++r) {
        int rl = (r & 3) + 8 * (r >> 2) + 4 * (l >> 5);
        int rt = stripe * 32 + rl;
        float t1 = sums[rt][0][0] + sums[rt][1][0] + sums[rt][2][0] + sums[rt][3][0];
        float t2 = sums[rt][0][1] + sums[rt][1][1] + sums[rt][2][1] + sums[rt][3][1];
        float mean = t1 * (1.f / 512.f);
        float var  = t2 * (1.f / 512.f) - mean * mean;
        float rs   = rsqrtf(var + 1e-5f);
        unsigned short* trow = tile + (size_t)rt * TPAD;
        #pragma unroll
        for (int tt = 0; tt < 4; ++tt) {
            int c = cbase + tt * 32;
            float ln  = (acc[tt][r] - mean) * rs * gev[tt] + bev[tt];
            float env = bf2f(trow[c]) + fmaxf(ln, 0.f);
            if (OUTBF) ((unsigned short*)eoutv)[(size_t)bi * 65536 + rt * 512 + c] = f2bf(env);
            else       ((float*)eoutv)[(size_t)bi * 32768 + rt * 512 + c] = env;
            float sg = 1.f / (1.f + __expf(-env));
            trow[c] = f2bf(__expf(sg));
        }
    }
    __syncthreads();

    // ---- softmax-over-j reduce + aggregate + fused x-update ----
    {
        int c = t;
        const float* uj = Ujx + (size_t)brow * CD + c;
        float den = 0.f, num = 0.f;
        #pragma unroll 8
        for (int j = 0; j < NNODE; ++j) {
            float wv = bf2f(tile[j * TPAD + c]);
            float uv = uj[(size_t)j * CD];
            den += wv; num = fmaf(wv, uv, num);
        }
        float aggv = num / (den * (float)NNODE);

        // x = relu(res + LN(XU + agg)) for row bi, channel c = t
        float v = XU[(size_t)bi * CD + c] + aggv;
        float s1x = v, s2x = v * v;
        #pragma unroll
        for (int off = 1; off < 64; off <<= 1) {
            s1x += __shfl_xor(s1x, off, 64);
            s2x += __shfl_xor(s2x, off, 64);
        }
        if (l == 0) { xs1[w] = s1x; xs2[w] = s2x; }
        __syncthreads();
        float t1 = 0.f, t2 = 0.f;
        #pragma unroll
        for (int ww = 0; ww < 8; ++ww) { t1 += xs1[ww]; t2 += xs2[ww]; }
        float mean = t1 * (1.f / 512.f);
        float var  = t2 * (1.f / 512.f) - mean * mean;
        float rs   = rsqrtf(var + 1e-5f);
        float ln   = (v - mean) * rs * gv[c] + bv[c];
        xout[(size_t)bi * CD + c] = fmaxf(xres[(size_t)bi * CD + c] + ln, 0.f);
    }
}

extern "C" void kernel_launch(void* const* d_in, const int* in_sizes, int n_in,
                              void* d_out, int out_size, void* d_ws, size_t ws_size,
                              hipStream_t stream)
{
    const float* x    = (const float*)d_in[0];
    const float* edge = (const float*)d_in[1];
    const float* W[10];
    for (int i = 0; i < 10; ++i) W[i] = (const float*)d_in[2 + i];
    // 0 WA1, 1 WB1, 2 WE1, 3 WU1, 4 WV1, 5 WA2, 6 WB2, 7 WE2, 8 WU2, 9 WV2
    const float* ge1 = (const float*)d_in[12];
    const float* gv1 = (const float*)d_in[13];
    const float* ge2 = (const float*)d_in[14];
    const float* gv2 = (const float*)d_in[15];
    const float* be1 = (const float*)d_in[16];
    const float* bv1 = (const float*)d_in[17];
    const float* be2 = (const float*)d_in[18];
    const float* bv2 = (const float*)d_in[19];

    char* wsb = (char*)d_ws;
    unsigned short* P32 = (unsigned short*)wsb;               // 10 x 512 KB = 5 MB
    float* Vix = (float*)(wsb + (size_t)6  * 1048576);
    float* Vjx = (float*)(wsb + (size_t)8  * 1048576);
    float* Ujx = (float*)(wsb + (size_t)10 * 1048576);
    float* XU  = (float*)(wsb + (size_t)12 * 1048576);
    float* x1  = (float*)(wsb + (size_t)16 * 1048576);

    float* xout  = (float*)d_out;
    float* eintF = xout + (size_t)524288;     // edge region (bf16 lives in slot's first half)

    // pack order: 0 WA1, 1 WB1, 2 WV1, 3 WU1, 4 WA2, 5 WB2, 6 WV2, 7 WU2, 8 WE1, 9 WE2
    pack32_k<<<dim3(32, 16, 10), 64, 0, stream>>>(
        W[0], W[1], W[4], W[3], W[5], W[6], W[9], W[8], W[2], W[7], P32);

#define PW(i) (P32 + (size_t)(i) * 262144)
    // ---- layer 1 ----
    proj_mfma<<<dim3(32, 4), 512, 0, stream>>>(x, PW(0), Vix, Vjx, Ujx, XU);
    edge_mfma<false, true><<<1024, 512, 0, stream>>>(edge, eintF, Vix, Vjx, Ujx,
                                                     PW(8), ge1, be1, XU, x, gv1, bv1, x1);
    // ---- layer 2 ----
    proj_mfma<<<dim3(32, 4), 512, 0, stream>>>(x1, PW(4), Vix, Vjx, Ujx, XU);
    edge_mfma<true, false><<<1024, 512, 0, stream>>>(eintF, eintF, Vix, Vjx, Ujx,
                                                     PW(9), ge2, be2, XU, x1, gv2, bv2, xout);
#undef PW
}